// Round 20
// baseline (2262.776 us; speedup 1.0000x reference)
//
#include <hip/hip_runtime.h>

#define TT   8192
#define DDIM 2048
#define HDIM 7168
#define NEXP 8
#define MT   32                 // Path-B M-tiles per expert (8192/256)
#define NT1  (HDIM / 128)       // 56 n-tiles gemm1 (128 w1 + 128 w3 cols each)
#define NT2  (DDIM / 256)       // 8 n-tiles gemm2
#define KSPL 4                  // gemm2 split-K (non-atomic bf16 partials)
#define NTILE_MAX 72            // sum ceil(cnt_e/256) <= 16384/256 + 8

typedef __attribute__((ext_vector_type(8))) short bf16x8;
typedef __attribute__((ext_vector_type(8))) short short8v;
typedef __attribute__((ext_vector_type(4))) short short4v;
typedef __attribute__((ext_vector_type(4))) float f32x4;

__device__ __forceinline__ unsigned short f2bf(float f) {
  unsigned int u = __builtin_bit_cast(unsigned int, f);
  u += 0x7fffu + ((u >> 16) & 1u);   // RNE
  return (unsigned short)(u >> 16);
}

__device__ __forceinline__ float bf2f(unsigned short h) {
  unsigned int u = ((unsigned int)h) << 16;
  return __builtin_bit_cast(float, u);
}

__device__ __forceinline__ void gload_lds16(const void* gp, void* lp) {
  __builtin_amdgcn_global_load_lds((__attribute__((address_space(1))) void*)gp,
                                   (__attribute__((address_space(3))) void*)lp,
                                   16, 0, 0);
}

__device__ __forceinline__ void mfma16(f32x4& c, bf16x8 a, bf16x8 b) {
  c = __builtin_amdgcn_mfma_f32_16x16x32_bf16(a, b, c, 0, 0, 0);
}

__device__ __forceinline__ void wg_barrier() {
  asm volatile("" ::: "memory");
  __builtin_amdgcn_s_barrier();
  asm volatile("" ::: "memory");
}

// ---- 8-phase schedule (r5/r6/r10/r15/r19-validated ledger) ----
#define PH(H, BA, BB, RDB, STG, SRCP, SOFF, VM)                              \
  do {                                                                       \
    if (RDB) {                                                               \
      _Pragma("unroll")                                                      \
      for (int n = 0; n < 4; ++n)                                            \
        bfr[n] = *(const bf16x8*)(smem + (BB) + rB + n * 1024);              \
    }                                                                        \
    _Pragma("unroll")                                                        \
    for (int m = 0; m < 4; ++m)                                              \
      af[m] = *(const bf16x8*)(smem + (BA) + rA + ((H) + m) * 1024);         \
    if ((STG) >= 0) {                                                        \
      gload_lds16(SRCP[0] + (SOFF), smem + (STG) + wid * 2048);              \
      gload_lds16(SRCP[1] + (SOFF), smem + (STG) + wid * 2048 + 1024);       \
    }                                                                        \
    wg_barrier();                                                            \
    __builtin_amdgcn_s_setprio(1);                                           \
    _Pragma("unroll")                                                        \
    for (int n = 0; n < 4; ++n) {                                            \
      _Pragma("unroll")                                                      \
      for (int m = 0; m < 4; ++m)                                            \
        mfma16(acc[(H) + m][n], af[m], bfr[n]);                              \
    }                                                                        \
    __builtin_amdgcn_s_setprio(0);                                           \
    if ((VM) == 6) asm volatile("s_waitcnt vmcnt(6)" ::: "memory");          \
    if ((VM) == 0) asm volatile("s_waitcnt vmcnt(0)" ::: "memory");          \
    wg_barrier();                                                            \
  } while (0)

#define ITER_FULL(kb)                                                        \
  PH(0, 0,     32768,  1, 81920,  asrc, (kb) + 192, -1);                     \
  PH(4, 0,     32768,  0, 32768,  bsrc, (kb) + 256, -1);                     \
  PH(0, 16384, 49152,  1, 0,      asrc, (kb) + 256, -1);                     \
  PH(4, 16384, 49152,  0, 49152,  bsrc, (kb) + 320,  6);                     \
  PH(0, 65536, 98304,  1, 16384,  asrc, (kb) + 320, -1);                     \
  PH(4, 65536, 98304,  0, 98304,  bsrc, (kb) + 384, -1);                     \
  PH(0, 81920, 114688, 1, 65536,  asrc, (kb) + 384, -1);                     \
  PH(4, 81920, 114688, 0, 114688, bsrc, (kb) + 448,  6);

#define ITER_LAST(kb)                                                        \
  PH(0, 0,     32768,  1, 81920,  asrc, (kb) + 192, -1);                     \
  PH(4, 0,     32768,  0, -1,     asrc, 0,          -1);                     \
  PH(0, 16384, 49152,  1, -1,     asrc, 0,          -1);                     \
  PH(4, 16384, 49152,  0, -1,     asrc, 0,           0);                     \
  PH(0, 65536, 98304,  1, -1,     asrc, 0,          -1);                     \
  PH(4, 65536, 98304,  0, -1,     asrc, 0,          -1);                     \
  PH(0, 81920, 114688, 1, -1,     asrc, 0,          -1);                     \
  PH(4, 81920, 114688, 0, -1,     asrc, 0,          -1);

#define PROLOGUE()                                                           \
  do {                                                                       \
    gload_lds16(asrc[0] + 0,   smem + 0      + wid * 2048);                  \
    gload_lds16(asrc[1] + 0,   smem + 0      + wid * 2048 + 1024);           \
    gload_lds16(bsrc[0] + 0,   smem + 32768  + wid * 2048);                  \
    gload_lds16(bsrc[1] + 0,   smem + 32768  + wid * 2048 + 1024);           \
    gload_lds16(asrc[0] + 64,  smem + 16384  + wid * 2048);                  \
    gload_lds16(asrc[1] + 64,  smem + 16384  + wid * 2048 + 1024);           \
    gload_lds16(bsrc[0] + 64,  smem + 49152  + wid * 2048);                  \
    gload_lds16(bsrc[1] + 64,  smem + 49152  + wid * 2048 + 1024);           \
    gload_lds16(bsrc[0] + 128, smem + 98304  + wid * 2048);                  \
    gload_lds16(bsrc[1] + 128, smem + 98304  + wid * 2048 + 1024);           \
    gload_lds16(asrc[0] + 128, smem + 65536  + wid * 2048);                  \
    gload_lds16(asrc[1] + 128, smem + 65536  + wid * 2048 + 1024);           \
    gload_lds16(bsrc[0] + 192, smem + 114688 + wid * 2048);                  \
    gload_lds16(bsrc[1] + 192, smem + 114688 + wid * 2048 + 1024);           \
    asm volatile("s_waitcnt vmcnt(6)" ::: "memory");                         \
    wg_barrier();                                                            \
  } while (0)

// ---------------- fp32 -> bf16 elementwise (8 elems/thread) ----------------
__global__ __launch_bounds__(256) void cvt_bf16_kernel(const float* __restrict__ src,
                                                       unsigned short* __restrict__ dst,
                                                       long n8) {
  long i = (long)blockIdx.x * 256 + threadIdx.x;
  long stride = (long)gridDim.x * 256;
  for (; i < n8; i += stride) {
    float4 a = ((const float4*)src)[i * 2];
    float4 b = ((const float4*)src)[i * 2 + 1];
    short8v s;
    s[0] = (short)f2bf(a.x); s[1] = (short)f2bf(a.y);
    s[2] = (short)f2bf(a.z); s[3] = (short)f2bf(a.w);
    s[4] = (short)f2bf(b.x); s[5] = (short)f2bf(b.y);
    s[6] = (short)f2bf(b.z); s[7] = (short)f2bf(b.w);
    ((short8v*)dst)[i] = s;
  }
}

// ---------------- gate (fused x -> bf16 conversion) ----------------
__global__ __launch_bounds__(256) void gate_kernel(const float* __restrict__ x,
                                                   const float* __restrict__ gw,
                                                   int* __restrict__ route_e,
                                                   float* __restrict__ route_w,
                                                   int* __restrict__ counts,
                                                   unsigned short* __restrict__ xbf) {
  int t = blockIdx.x;
  int tid = threadIdx.x;
  const float* xr = x + (size_t)t * DDIM;
  unsigned short* xo = xbf + (size_t)t * DDIM;
  float p[NEXP];
#pragma unroll
  for (int e = 0; e < NEXP; ++e) p[e] = 0.f;
#pragma unroll
  for (int c = 0; c < DDIM / (256 * 4); ++c) {
    int d = (c * 256 + tid) * 4;
    float4 xv = *(const float4*)(xr + d);
    short4v s;
    s[0] = (short)f2bf(xv.x); s[1] = (short)f2bf(xv.y);
    s[2] = (short)f2bf(xv.z); s[3] = (short)f2bf(xv.w);
    *(short4v*)(xo + d) = s;
#pragma unroll
    for (int e = 0; e < NEXP; ++e) {
      float4 wv = *(const float4*)(gw + (size_t)e * DDIM + d);
      p[e] += xv.x * wv.x + xv.y * wv.y + xv.z * wv.z + xv.w * wv.w;
    }
  }
  __shared__ float red[NEXP][4];
  int lane = tid & 63, wid = tid >> 6;
#pragma unroll
  for (int e = 0; e < NEXP; ++e) {
    float v = p[e];
    for (int o = 32; o > 0; o >>= 1) v += __shfl_down(v, o);
    if (lane == 0) red[e][wid] = v;
  }
  __syncthreads();
  if (tid == 0) {
    float lg[NEXP];
#pragma unroll
    for (int e = 0; e < NEXP; ++e) lg[e] = red[e][0] + red[e][1] + red[e][2] + red[e][3];
    int i0 = 0;
#pragma unroll
    for (int e = 1; e < NEXP; ++e) if (lg[e] > lg[i0]) i0 = e;
    int i1 = -1;
#pragma unroll
    for (int e = 0; e < NEXP; ++e) {
      if (e == i0) continue;
      if (i1 < 0 || lg[e] > lg[i1]) i1 = e;
    }
    float w0 = 1.f / (1.f + __expf(lg[i1] - lg[i0]));
    float w1 = 1.f - w0;
    route_e[t * 2 + 0] = i0;  route_e[t * 2 + 1] = i1;
    route_w[t * 2 + 0] = w0;  route_w[t * 2 + 1] = w1;
    atomicAdd(&counts[i0], 1);
    atomicAdd(&counts[i1], 1);
  }
}

// scan + compact tile map: tmap[0] = ntile; tmap[1+i] = (e<<16)|mt
__global__ void scan_kernel(const int* __restrict__ counts, int* __restrict__ offsets,
                            int* __restrict__ cursor, int* __restrict__ tmap) {
  if (threadIdx.x == 0 && blockIdx.x == 0) {
    int o = 0, idx = 0;
    for (int e = 0; e < NEXP; ++e) {
      offsets[e] = o; cursor[e] = o;
      int c = counts[e]; o += c;
      for (int t = 0; t * 256 < c && idx < NTILE_MAX; ++t) tmap[1 + idx++] = (e << 16) | t;
    }
    tmap[0] = idx;
  }
}

__global__ __launch_bounds__(256) void scatter_kernel(const int* __restrict__ route_e,
                                                      const float* __restrict__ route_w,
                                                      int* __restrict__ cursor,
                                                      int* __restrict__ tok_list,
                                                      float* __restrict__ tok_w,
                                                      int* __restrict__ slot_of) {
  int t = blockIdx.x * 256 + threadIdx.x;
  if (t >= TT) return;
#pragma unroll
  for (int s = 0; s < 2; ++s) {
    int e = route_e[t * 2 + s];
    int p = atomicAdd(&cursor[e], 1);
    tok_list[p] = t;
    tok_w[p] = route_w[t * 2 + s];
    slot_of[t * 2 + s] = p;
  }
}

// ---------------- w2 [H,D] fp32 -> w2t [D,H] bf16 ----------------
__global__ __launch_bounds__(256) void transpose_w2_kernel(const float* __restrict__ w2,
                                                           unsigned short* __restrict__ w2t,
                                                           int expert_fixed) {
  int e = expert_fixed >= 0 ? expert_fixed : (int)blockIdx.z;
  const float* src = w2 + (size_t)e * HDIM * DDIM;
  unsigned short* dst = w2t + (expert_fixed >= 0 ? (size_t)0 : (size_t)e * DDIM * HDIM);
  int h0 = blockIdx.x * 64, d0 = blockIdx.y * 64;
  __shared__ __align__(8) unsigned short tile[64 * 66];
  int tid = threadIdx.x;
  int hr = tid >> 2;
#pragma unroll
  for (int j = 0; j < 4; ++j) {
    int f4 = (tid & 3) + j * 4;
    float4 v = *(const float4*)(src + (size_t)(h0 + hr) * DDIM + d0 + f4 * 4);
    unsigned int lo = (unsigned int)f2bf(v.x) | ((unsigned int)f2bf(v.y) << 16);
    unsigned int hi = (unsigned int)f2bf(v.z) | ((unsigned int)f2bf(v.w) << 16);
    char* bp = (char*)tile + hr * 132 + f4 * 8;
    *(unsigned int*)bp = lo;
    *(unsigned int*)(bp + 4) = hi;
  }
  __syncthreads();
  int dr = tid >> 2;
  int hbase = (tid & 3) * 16;
  unsigned short vals[16];
#pragma unroll
  for (int i = 0; i < 16; ++i)
    vals[i] = *(unsigned short*)((char*)tile + (hbase + i) * 132 + dr * 2);
  unsigned short* op = dst + (size_t)(d0 + dr) * HDIM + h0 + hbase;
  short8v s0, s1;
#pragma unroll
  for (int i = 0; i < 8; ++i) { s0[i] = (short)vals[i]; s1[i] = (short)vals[i + 8]; }
  *(short8v*)(op) = s0;
  *(short8v*)(op + 8) = s1;
}

// ---- final reduce: out[t] = sum_s w_s * sum_ks y[ks][slot_s] ----
__global__ __launch_bounds__(256) void reduce_kernel(const unsigned short* __restrict__ ybuf,
                                                     const int* __restrict__ slot_of,
                                                     const float* __restrict__ route_w,
                                                     float* __restrict__ out) {
  const size_t YSZ = (size_t)TT * 2 * DDIM;     // elements per K-part buffer
  int t = blockIdx.x;
  int d = threadIdx.x * 8;
  int s0 = slot_of[t * 2 + 0], s1 = slot_of[t * 2 + 1];
  float w0 = route_w[t * 2 + 0], w1 = route_w[t * 2 + 1];
  float v0[8], v1[8];
#pragma unroll
  for (int j = 0; j < 8; ++j) { v0[j] = 0.f; v1[j] = 0.f; }
#pragma unroll
  for (int ks = 0; ks < KSPL; ++ks) {
    bf16x8 y0 = *(const bf16x8*)(ybuf + (size_t)ks * YSZ + (size_t)s0 * DDIM + d);
    bf16x8 y1 = *(const bf16x8*)(ybuf + (size_t)ks * YSZ + (size_t)s1 * DDIM + d);
#pragma unroll
    for (int j = 0; j < 8; ++j) {
      v0[j] += bf2f((unsigned short)y0[j]);
      v1[j] += bf2f((unsigned short)y1[j]);
    }
  }
  float* op = out + (size_t)t * DDIM + d;
#pragma unroll
  for (int j = 0; j < 8; ++j)
    op[j] = w0 * v0[j] + w1 * v1[j];
}

// =====================================================================
// GEMM1: g = silu(Xe w1^T) * (Xe w3^T); 256x256 tile, BK=64, 8 waves,
// r15 schedule; compact grid via tmap (r13-validated).
// =====================================================================
__global__ __launch_bounds__(512, 2) void gemm1_kernel(
    const unsigned short* __restrict__ xbf, const unsigned short* __restrict__ w1b,
    const unsigned short* __restrict__ w3b, const int* __restrict__ tok_list,
    const int* __restrict__ counts, const int* __restrict__ offsets,
    const int* __restrict__ tmap,
    unsigned short* __restrict__ g, int expert_fixed) {
  __shared__ __align__(16) char smem[133120];
  constexpr int NI = DDIM / 128;                // 16 iterations (2 K-tiles each)

  int nwg = gridDim.x;
  int orig = blockIdx.x;
  int wg = (orig & 7) * (nwg >> 3) + (orig >> 3);   // bijective XCD swizzle (nwg%8==0)
  int e, mbase, nt;
  if (expert_fixed >= 0) {
    e = expert_fixed;
    mbase = (wg & (MT - 1)) * 256;
    nt = (wg >> 5) % NT1;
  } else {
    int tl = wg % NTILE_MAX;
    nt = wg / NTILE_MAX;
    if (tl >= tmap[0]) return;
    int pk = tmap[1 + tl];
    e = pk >> 16;
    mbase = (pk & 0xffff) * 256;
  }
  int cnt = counts[e];
  if (mbase >= cnt) return;
  int off = offsets[e];
  int gshift = expert_fixed >= 0 ? 0 : off;
  int rows = cnt - mbase; if (rows > 256) rows = 256;

  const unsigned short* w1e = expert_fixed >= 0 ? w1b : w1b + (size_t)e * HDIM * DDIM;
  const unsigned short* w3e = expert_fixed >= 0 ? w3b : w3b + (size_t)e * HDIM * DDIM;

  int tid = threadIdx.x, lane = tid & 63, wid = tid >> 6;
  int wr = wid >> 2, wc = wid & 3;

  int r16 = lane >> 2;
  int csrc = (lane & 3) ^ ((lane >> 3) & 3);
  const char* asrc[2]; const char* bsrc[2];
#pragma unroll
  for (int j = 0; j < 2; ++j) {
    int r = wid * 32 + j * 16 + r16;
    int m = mbase + r; if (m > cnt - 1) m = cnt - 1;
    int tok = tok_list[off + m];
    asrc[j] = (const char*)xbf + (size_t)tok * (DDIM * 2) + csrc * 16;
    const char* base = (r < 128)
        ? (const char*)w1e + (size_t)(nt * 128 + r) * (DDIM * 2)
        : (const char*)w3e + (size_t)(nt * 128 + r - 128) * (DDIM * 2);
    bsrc[j] = base + csrc * 16;
  }
  int rA = (wr * 128 + (lane & 15)) * 64 + (((lane >> 4) ^ ((lane >> 1) & 3)) * 16);
  int rB = (wc * 64  + (lane & 15)) * 64 + (((lane >> 4) ^ ((lane >> 1) & 3)) * 16);

  f32x4 zv = {0.f, 0.f, 0.f, 0.f};
  f32x4 acc[8][4];
#pragma unroll
  for (int m = 0; m < 8; ++m)
#pragma unroll
    for (int n = 0; n < 4; ++n) acc[m][n] = zv;
  bf16x8 af[4], bfr[4];

  PROLOGUE();
#pragma unroll 1
  for (int i = 0; i < NI - 1; ++i) {
    size_t kb = (size_t)i * 256;
    ITER_FULL(kb);
  }
  {
    size_t kb = (size_t)(NI - 1) * 256;
    ITER_LAST(kb);
  }

  // epilogue: h1 (wc<2) -> LDS; h3 (wc>=2) computes g = silu(h1)*h3
  float* hb = (float*)smem;                       // [256][130] f32
  if (wc < 2) {
#pragma unroll
    for (int m = 0; m < 8; ++m)
#pragma unroll
      for (int q = 0; q < 4; ++q) {
        int row = wr * 128 + m * 16 + (lane >> 4) * 4 + q;
        int col = wc * 64 + (lane & 15);
#pragma unroll
        for (int n = 0; n < 4; ++n)
          hb[row * 130 + col + n * 16] = acc[m][n][q];
      }
  }
  asm volatile("s_waitcnt lgkmcnt(0)" ::: "memory");
  wg_barrier();
  if (wc >= 2) {
#pragma unroll
    for (int m = 0; m < 8; ++m)
#pragma unroll
      for (int q = 0; q < 4; ++q) {
        int row = wr * 128 + m * 16 + (lane >> 4) * 4 + q;
        if (row >= rows) continue;
        size_t grow = (size_t)(mbase + row + gshift);
        int colbase = (wc - 2) * 64 + (lane & 15);
        unsigned short* gp = g + grow * HDIM + nt * 128 + colbase;
#pragma unroll
        for (int n = 0; n < 4; ++n) {
          float h1 = hb[row * 130 + colbase + n * 16];
          float h3 = acc[m][n][q];
          float gv = (h1 / (1.f + __expf(-h1))) * h3;
          gp[n * 16] = f2bf(gv);
        }
      }
  }
}

// =====================================================================
// GEMM2: y = g @ w2 per packed slot; split-K=4 (non-atomic bf16 partial
// per K-quarter into ybuf[ks]); nt/ks-fast decode; Path B: atomic f32.
// =====================================================================
__global__ __launch_bounds__(512, 2) void gemm2_kernel(
    const unsigned short* __restrict__ g, const unsigned short* __restrict__ w2t,
    const int* __restrict__ tok_list, const float* __restrict__ tok_w,
    const int* __restrict__ counts, const int* __restrict__ offsets,
    const int* __restrict__ tmap,
    unsigned short* __restrict__ ybuf, float* __restrict__ out, int expert_fixed) {
  __shared__ __align__(16) char smem[131072];
  constexpr int NI = HDIM / 128 / KSPL;         // 14 iterations per K-quarter

  int nwg = gridDim.x;
  int orig = blockIdx.x;
  int wg = (orig & 7) * (nwg >> 3) + (orig >> 3);
  int e, mbase, nt, ks;
  if (expert_fixed >= 0) {
    e = expert_fixed;
    nt = wg % NT2;
    ks = (wg / NT2) % KSPL;
    mbase = (wg / (NT2 * KSPL)) * 256;
  } else {
    nt = wg % NT2;
    ks = (wg / NT2) % KSPL;
    int tl = wg / (NT2 * KSPL);   // nt,ks fast: 32 blocks of a tile adjacent
    if (tl >= tmap[0]) return;
    int pk = tmap[1 + tl];
    e = pk >> 16;
    mbase = (pk & 0xffff) * 256;
  }
  int cnt = counts[e];
  if (mbase >= cnt) return;
  int off = offsets[e];
  int gshift = expert_fixed >= 0 ? 0 : off;
  int nbase = nt * 256;
  int rows = cnt - mbase; if (rows > 256) rows = 256;
  const unsigned short* w2te = w2t + (expert_fixed >= 0 ? (size_t)0 : (size_t)e * DDIM * HDIM);
  size_t koff = (size_t)ks * (NI * 256);        // byte offset of this K-window

  int tid = threadIdx.x, lane = tid & 63, wid = tid >> 6;
  int wr = wid >> 2, wc = wid & 3;

  int r16 = lane >> 2;
  int csrc = (lane & 3) ^ ((lane >> 3) & 3);
  const char* asrc[2]; const char* bsrc[2];
#pragma unroll
  for (int j = 0; j < 2; ++j) {
    int r = wid * 32 + j * 16 + r16;
    int m = mbase + r; if (m > cnt - 1) m = cnt - 1;
    asrc[j] = (const char*)g + (size_t)(m + gshift) * (HDIM * 2) + csrc * 16 + koff;
    bsrc[j] = (const char*)w2te + (size_t)(nbase + r) * (HDIM * 2) + csrc * 16 + koff;
  }
  int rA = (wr * 128 + (lane & 15)) * 64 + (((lane >> 4) ^ ((lane >> 1) & 3)) * 16);
  int rB = (wc * 64  + (lane & 15)) * 64 + (((lane >> 4) ^ ((lane >> 1) & 3)) * 16);

  f32x4 zv = {0.f, 0.f, 0.f, 0.f};
  f32x4 acc[8][4];
#pragma unroll
  for (int m = 0; m < 8; ++m)
#pragma unroll
    for (int n = 0; n < 4; ++n) acc[m][n] = zv;
  bf16x8 af[4], bfr[4];

  PROLOGUE();
#pragma unroll 1
  for (int i = 0; i < NI - 1; ++i) {
    size_t kb = (size_t)i * 256;
    ITER_FULL(kb);
  }
  {
    size_t kb = (size_t)(NI - 1) * 256;
    ITER_LAST(kb);
  }

  if (ybuf) {
    unsigned short* yb = ybuf + (size_t)ks * ((size_t)TT * 2 * DDIM);
#pragma unroll
    for (int m = 0; m < 8; ++m)
#pragma unroll
      for (int q = 0; q < 4; ++q) {
        int row = wr * 128 + m * 16 + (lane >> 4) * 4 + q;
        if (row >= rows) continue;
        size_t slot = (size_t)(off + mbase + row);
        unsigned short* yp = yb + slot * DDIM + nbase + wc * 64 + (lane & 15);
#pragma unroll
        for (int n = 0; n < 4; ++n)
          yp[n * 16] = f2bf(acc[m][n][q]);
      }
  } else {
#pragma unroll
    for (int m = 0; m < 8; ++m)
#pragma unroll
      for (int q = 0; q < 4; ++q) {
        int row = wr * 128 + m * 16 + (lane >> 4) * 4 + q;
        if (row >= rows) continue;
        int mi = mbase + row;
        int tok = tok_list[off + mi];
        float wt = tok_w[off + mi];
        float* op = out + (size_t)tok * DDIM + nbase + wc * 64 + (lane & 15);
#pragma unroll
        for (int n = 0; n < 4; ++n)
          atomicAdd(op + n * 16, acc[m][n][q] * wt);
      }
  }
}

extern "C" void kernel_launch(void* const* d_in, const int* in_sizes, int n_in,
                              void* d_out, int out_size, void* d_ws, size_t ws_size,
                              hipStream_t stream) {
  const float* x      = (const float*)d_in[0];
  const float* gate_w = (const float*)d_in[1];
  const float* w1     = (const float*)d_in[2];
  const float* w2     = (const float*)d_in[3];
  const float* w3     = (const float*)d_in[4];
  float* out = (float*)d_out;
  char* ws = (char*)d_ws;

  size_t o = 0;
  int* counts  = (int*)(ws + o);
  int* offsets = counts + 8;
  int* cursor  = counts + 16;
  int* tmap    = counts + 24;          // tmap[0]=ntile, entries 1..NTILE_MAX
  o += 1024;
  int*   route_e = (int*)(ws + o);   o += (size_t)TT * 2 * 4;
  float* route_w = (float*)(ws + o); o += (size_t)TT * 2 * 4;
  int*   tok_list = (int*)(ws + o);  o += (size_t)TT * 2 * 4;
  float* tok_w = (float*)(ws + o);   o += (size_t)TT * 2 * 4;
  int*   slot_of = (int*)(ws + o);   o += (size_t)TT * 2 * 4;
  unsigned short* xbf = (unsigned short*)(ws + o); o += (size_t)TT * DDIM * 2;
  size_t fixed = o;

  const size_t WSZ = (size_t)HDIM * DDIM;
  const size_t wbf_full = (size_t)NEXP * WSZ * 2;
  const size_t gfull = (size_t)TT * 2 * HDIM * 2;

  hipMemsetAsync(counts, 0, 8 * sizeof(int), stream);
  gate_kernel<<<TT, 256, 0, stream>>>(x, gate_w, route_e, route_w, counts, xbf);
  scan_kernel<<<1, 64, 0, stream>>>(counts, offsets, cursor, tmap);
  scatter_kernel<<<(TT + 255) / 256, 256, 0, stream>>>(route_e, route_w, cursor,
                                                       tok_list, tok_w, slot_of);

  if (ws_size >= fixed + 3 * wbf_full + gfull) {
    unsigned short* w1b = (unsigned short*)(ws + fixed);
    unsigned short* w3b = w1b + NEXP * WSZ;
    unsigned short* w2t = w3b + NEXP * WSZ;
    unsigned short* gbuf = w2t + NEXP * WSZ;
    // ybuf: 4 K-quarter partial buffers (4 x 67MB = 268MB) alias w1b+w3b
    // (470MB contiguous, both dead after gemm1)
    unsigned short* ybuf = w1b;
    cvt_bf16_kernel<<<8192, 256, 0, stream>>>(w1, w1b, (long)(NEXP * WSZ / 8));
    cvt_bf16_kernel<<<8192, 256, 0, stream>>>(w3, w3b, (long)(NEXP * WSZ / 8));
    transpose_w2_kernel<<<dim3(HDIM / 64, DDIM / 64, NEXP), 256, 0, stream>>>(w2, w2t, -1);
    gemm1_kernel<<<NTILE_MAX * NT1, 512, 0, stream>>>(
        xbf, w1b, w3b, tok_list, counts, offsets, tmap, gbuf, -1);
    gemm2_kernel<<<NTILE_MAX * NT2 * KSPL, 512, 0, stream>>>(
        gbuf, w2t, tok_list, tok_w, counts, offsets, tmap, ybuf, out, -1);
    reduce_kernel<<<TT, 256, 0, stream>>>(ybuf, slot_of, route_w, out);
  } else {
    unsigned short* w1b = (unsigned short*)(ws + fixed);
    unsigned short* w3b = w1b + WSZ;
    unsigned short* w2t = w3b + WSZ;
    unsigned short* gbuf = w2t + WSZ;
    hipMemsetAsync(out, 0, (size_t)TT * DDIM * sizeof(float), stream);
    for (int e = 0; e < NEXP; ++e) {
      cvt_bf16_kernel<<<4096, 256, 0, stream>>>(w1 + (size_t)e * WSZ, w1b, (long)(WSZ / 8));
      cvt_bf16_kernel<<<4096, 256, 0, stream>>>(w3 + (size_t)e * WSZ, w3b, (long)(WSZ / 8));
      transpose_w2_kernel<<<dim3(HDIM / 64, DDIM / 64, 1), 256, 0, stream>>>(w2, w2t, e);
      gemm1_kernel<<<MT * NT1, 512, 0, stream>>>(
          xbf, w1b, w3b, tok_list, counts, offsets, tmap, gbuf, e);
      gemm2_kernel<<<MT * NT2 * KSPL, 512, 0, stream>>>(
          gbuf, w2t, tok_list, tok_w, counts, offsets, tmap, (unsigned short*)0, out, e);
    }
  }
}

// Round 21
// 2195.208 us; speedup vs baseline: 1.0308x; 1.0308x over previous
//
#include <hip/hip_runtime.h>

#define TT   8192
#define DDIM 2048
#define HDIM 7168
#define NEXP 8
#define MT   32                 // Path-B M-tiles per expert (8192/256)
#define NT1  (HDIM / 128)       // 56 n-tiles gemm1 (128 w1 + 128 w3 cols each)
#define NT2  (DDIM / 256)       // 8 n-tiles gemm2
#define KSPL 2                  // gemm2 split-K (non-atomic bf16 partials)
#define NTILE_MAX 72            // sum ceil(cnt_e/256) <= 16384/256 + 8

typedef __attribute__((ext_vector_type(8))) short bf16x8;
typedef __attribute__((ext_vector_type(8))) short short8v;
typedef __attribute__((ext_vector_type(4))) short short4v;
typedef __attribute__((ext_vector_type(4))) float f32x4;

__device__ __forceinline__ unsigned short f2bf(float f) {
  unsigned int u = __builtin_bit_cast(unsigned int, f);
  u += 0x7fffu + ((u >> 16) & 1u);   // RNE
  return (unsigned short)(u >> 16);
}

__device__ __forceinline__ float bf2f(unsigned short h) {
  unsigned int u = ((unsigned int)h) << 16;
  return __builtin_bit_cast(float, u);
}

__device__ __forceinline__ void gload_lds16(const void* gp, void* lp) {
  __builtin_amdgcn_global_load_lds((__attribute__((address_space(1))) void*)gp,
                                   (__attribute__((address_space(3))) void*)lp,
                                   16, 0, 0);
}

__device__ __forceinline__ void mfma16(f32x4& c, bf16x8 a, bf16x8 b) {
  c = __builtin_amdgcn_mfma_f32_16x16x32_bf16(a, b, c, 0, 0, 0);
}

__device__ __forceinline__ void wg_barrier() {
  asm volatile("" ::: "memory");
  __builtin_amdgcn_s_barrier();
  asm volatile("" ::: "memory");
}

// ---- 8-phase schedule (r5/r6/r10/r15/r19-validated ledger) ----
#define PH(H, BA, BB, RDB, STG, SRCP, SOFF, VM)                              \
  do {                                                                       \
    if (RDB) {                                                               \
      _Pragma("unroll")                                                      \
      for (int n = 0; n < 4; ++n)                                            \
        bfr[n] = *(const bf16x8*)(smem + (BB) + rB + n * 1024);              \
    }                                                                        \
    _Pragma("unroll")                                                        \
    for (int m = 0; m < 4; ++m)                                              \
      af[m] = *(const bf16x8*)(smem + (BA) + rA + ((H) + m) * 1024);         \
    if ((STG) >= 0) {                                                        \
      gload_lds16(SRCP[0] + (SOFF), smem + (STG) + wid * 2048);              \
      gload_lds16(SRCP[1] + (SOFF), smem + (STG) + wid * 2048 + 1024);       \
    }                                                                        \
    wg_barrier();                                                            \
    __builtin_amdgcn_s_setprio(1);                                           \
    _Pragma("unroll")                                                        \
    for (int n = 0; n < 4; ++n) {                                            \
      _Pragma("unroll")                                                      \
      for (int m = 0; m < 4; ++m)                                            \
        mfma16(acc[(H) + m][n], af[m], bfr[n]);                              \
    }                                                                        \
    __builtin_amdgcn_s_setprio(0);                                           \
    if ((VM) == 6) asm volatile("s_waitcnt vmcnt(6)" ::: "memory");          \
    if ((VM) == 0) asm volatile("s_waitcnt vmcnt(0)" ::: "memory");          \
    wg_barrier();                                                            \
  } while (0)

#define ITER_FULL(kb)                                                        \
  PH(0, 0,     32768,  1, 81920,  asrc, (kb) + 192, -1);                     \
  PH(4, 0,     32768,  0, 32768,  bsrc, (kb) + 256, -1);                     \
  PH(0, 16384, 49152,  1, 0,      asrc, (kb) + 256, -1);                     \
  PH(4, 16384, 49152,  0, 49152,  bsrc, (kb) + 320,  6);                     \
  PH(0, 65536, 98304,  1, 16384,  asrc, (kb) + 320, -1);                     \
  PH(4, 65536, 98304,  0, 98304,  bsrc, (kb) + 384, -1);                     \
  PH(0, 81920, 114688, 1, 65536,  asrc, (kb) + 384, -1);                     \
  PH(4, 81920, 114688, 0, 114688, bsrc, (kb) + 448,  6);

#define ITER_LAST(kb)                                                        \
  PH(0, 0,     32768,  1, 81920,  asrc, (kb) + 192, -1);                     \
  PH(4, 0,     32768,  0, -1,     asrc, 0,          -1);                     \
  PH(0, 16384, 49152,  1, -1,     asrc, 0,          -1);                     \
  PH(4, 16384, 49152,  0, -1,     asrc, 0,           0);                     \
  PH(0, 65536, 98304,  1, -1,     asrc, 0,          -1);                     \
  PH(4, 65536, 98304,  0, -1,     asrc, 0,          -1);                     \
  PH(0, 81920, 114688, 1, -1,     asrc, 0,          -1);                     \
  PH(4, 81920, 114688, 0, -1,     asrc, 0,          -1);

#define PROLOGUE()                                                           \
  do {                                                                       \
    gload_lds16(asrc[0] + 0,   smem + 0      + wid * 2048);                  \
    gload_lds16(asrc[1] + 0,   smem + 0      + wid * 2048 + 1024);           \
    gload_lds16(bsrc[0] + 0,   smem + 32768  + wid * 2048);                  \
    gload_lds16(bsrc[1] + 0,   smem + 32768  + wid * 2048 + 1024);           \
    gload_lds16(asrc[0] + 64,  smem + 16384  + wid * 2048);                  \
    gload_lds16(asrc[1] + 64,  smem + 16384  + wid * 2048 + 1024);           \
    gload_lds16(bsrc[0] + 64,  smem + 49152  + wid * 2048);                  \
    gload_lds16(bsrc[1] + 64,  smem + 49152  + wid * 2048 + 1024);           \
    gload_lds16(bsrc[0] + 128, smem + 98304  + wid * 2048);                  \
    gload_lds16(bsrc[1] + 128, smem + 98304  + wid * 2048 + 1024);           \
    gload_lds16(asrc[0] + 128, smem + 65536  + wid * 2048);                  \
    gload_lds16(asrc[1] + 128, smem + 65536  + wid * 2048 + 1024);           \
    gload_lds16(bsrc[0] + 192, smem + 114688 + wid * 2048);                  \
    gload_lds16(bsrc[1] + 192, smem + 114688 + wid * 2048 + 1024);           \
    asm volatile("s_waitcnt vmcnt(6)" ::: "memory");                         \
    wg_barrier();                                                            \
  } while (0)

// ---------------- fp32 -> bf16 elementwise (8 elems/thread) ----------------
__global__ __launch_bounds__(256) void cvt_bf16_kernel(const float* __restrict__ src,
                                                       unsigned short* __restrict__ dst,
                                                       long n8) {
  long i = (long)blockIdx.x * 256 + threadIdx.x;
  long stride = (long)gridDim.x * 256;
  for (; i < n8; i += stride) {
    float4 a = ((const float4*)src)[i * 2];
    float4 b = ((const float4*)src)[i * 2 + 1];
    short8v s;
    s[0] = (short)f2bf(a.x); s[1] = (short)f2bf(a.y);
    s[2] = (short)f2bf(a.z); s[3] = (short)f2bf(a.w);
    s[4] = (short)f2bf(b.x); s[5] = (short)f2bf(b.y);
    s[6] = (short)f2bf(b.z); s[7] = (short)f2bf(b.w);
    ((short8v*)dst)[i] = s;
  }
}

// ---------------- gate (fused x -> bf16 conversion) ----------------
__global__ __launch_bounds__(256) void gate_kernel(const float* __restrict__ x,
                                                   const float* __restrict__ gw,
                                                   int* __restrict__ route_e,
                                                   float* __restrict__ route_w,
                                                   int* __restrict__ counts,
                                                   unsigned short* __restrict__ xbf) {
  int t = blockIdx.x;
  int tid = threadIdx.x;
  const float* xr = x + (size_t)t * DDIM;
  unsigned short* xo = xbf + (size_t)t * DDIM;
  float p[NEXP];
#pragma unroll
  for (int e = 0; e < NEXP; ++e) p[e] = 0.f;
#pragma unroll
  for (int c = 0; c < DDIM / (256 * 4); ++c) {
    int d = (c * 256 + tid) * 4;
    float4 xv = *(const float4*)(xr + d);
    short4v s;
    s[0] = (short)f2bf(xv.x); s[1] = (short)f2bf(xv.y);
    s[2] = (short)f2bf(xv.z); s[3] = (short)f2bf(xv.w);
    *(short4v*)(xo + d) = s;
#pragma unroll
    for (int e = 0; e < NEXP; ++e) {
      float4 wv = *(const float4*)(gw + (size_t)e * DDIM + d);
      p[e] += xv.x * wv.x + xv.y * wv.y + xv.z * wv.z + xv.w * wv.w;
    }
  }
  __shared__ float red[NEXP][4];
  int lane = tid & 63, wid = tid >> 6;
#pragma unroll
  for (int e = 0; e < NEXP; ++e) {
    float v = p[e];
    for (int o = 32; o > 0; o >>= 1) v += __shfl_down(v, o);
    if (lane == 0) red[e][wid] = v;
  }
  __syncthreads();
  if (tid == 0) {
    float lg[NEXP];
#pragma unroll
    for (int e = 0; e < NEXP; ++e) lg[e] = red[e][0] + red[e][1] + red[e][2] + red[e][3];
    int i0 = 0;
#pragma unroll
    for (int e = 1; e < NEXP; ++e) if (lg[e] > lg[i0]) i0 = e;
    int i1 = -1;
#pragma unroll
    for (int e = 0; e < NEXP; ++e) {
      if (e == i0) continue;
      if (i1 < 0 || lg[e] > lg[i1]) i1 = e;
    }
    float w0 = 1.f / (1.f + __expf(lg[i1] - lg[i0]));
    float w1 = 1.f - w0;
    route_e[t * 2 + 0] = i0;  route_e[t * 2 + 1] = i1;
    route_w[t * 2 + 0] = w0;  route_w[t * 2 + 1] = w1;
    atomicAdd(&counts[i0], 1);
    atomicAdd(&counts[i1], 1);
  }
}

// scan + compact tile map: tmap[0] = ntile; tmap[1+i] = (e<<16)|mt
__global__ void scan_kernel(const int* __restrict__ counts, int* __restrict__ offsets,
                            int* __restrict__ cursor, int* __restrict__ tmap) {
  if (threadIdx.x == 0 && blockIdx.x == 0) {
    int o = 0, idx = 0;
    for (int e = 0; e < NEXP; ++e) {
      offsets[e] = o; cursor[e] = o;
      int c = counts[e]; o += c;
      for (int t = 0; t * 256 < c && idx < NTILE_MAX; ++t) tmap[1 + idx++] = (e << 16) | t;
    }
    tmap[0] = idx;
  }
}

__global__ __launch_bounds__(256) void scatter_kernel(const int* __restrict__ route_e,
                                                      const float* __restrict__ route_w,
                                                      int* __restrict__ cursor,
                                                      int* __restrict__ tok_list,
                                                      float* __restrict__ tok_w,
                                                      int* __restrict__ slot_of) {
  int t = blockIdx.x * 256 + threadIdx.x;
  if (t >= TT) return;
#pragma unroll
  for (int s = 0; s < 2; ++s) {
    int e = route_e[t * 2 + s];
    int p = atomicAdd(&cursor[e], 1);
    tok_list[p] = t;
    tok_w[p] = route_w[t * 2 + s];
    slot_of[t * 2 + s] = p;
  }
}

// ---------------- w2 [H,D] fp32 -> w2t [D,H] bf16 ----------------
__global__ __launch_bounds__(256) void transpose_w2_kernel(const float* __restrict__ w2,
                                                           unsigned short* __restrict__ w2t,
                                                           int expert_fixed) {
  int e = expert_fixed >= 0 ? expert_fixed : (int)blockIdx.z;
  const float* src = w2 + (size_t)e * HDIM * DDIM;
  unsigned short* dst = w2t + (expert_fixed >= 0 ? (size_t)0 : (size_t)e * DDIM * HDIM);
  int h0 = blockIdx.x * 64, d0 = blockIdx.y * 64;
  __shared__ __align__(8) unsigned short tile[64 * 66];
  int tid = threadIdx.x;
  int hr = tid >> 2;
#pragma unroll
  for (int j = 0; j < 4; ++j) {
    int f4 = (tid & 3) + j * 4;
    float4 v = *(const float4*)(src + (size_t)(h0 + hr) * DDIM + d0 + f4 * 4);
    unsigned int lo = (unsigned int)f2bf(v.x) | ((unsigned int)f2bf(v.y) << 16);
    unsigned int hi = (unsigned int)f2bf(v.z) | ((unsigned int)f2bf(v.w) << 16);
    char* bp = (char*)tile + hr * 132 + f4 * 8;
    *(unsigned int*)bp = lo;
    *(unsigned int*)(bp + 4) = hi;
  }
  __syncthreads();
  int dr = tid >> 2;
  int hbase = (tid & 3) * 16;
  unsigned short vals[16];
#pragma unroll
  for (int i = 0; i < 16; ++i)
    vals[i] = *(unsigned short*)((char*)tile + (hbase + i) * 132 + dr * 2);
  unsigned short* op = dst + (size_t)(d0 + dr) * HDIM + h0 + hbase;
  short8v s0, s1;
#pragma unroll
  for (int i = 0; i < 8; ++i) { s0[i] = (short)vals[i]; s1[i] = (short)vals[i + 8]; }
  *(short8v*)(op) = s0;
  *(short8v*)(op + 8) = s1;
}

// ---- final reduce: out[t] = sum_s w_s * sum_ks y[ks][slot_s] ----
__global__ __launch_bounds__(256) void reduce_kernel(const unsigned short* __restrict__ ybuf,
                                                     const int* __restrict__ slot_of,
                                                     const float* __restrict__ route_w,
                                                     float* __restrict__ out) {
  const size_t YSZ = (size_t)TT * 2 * DDIM;     // elements per K-part buffer
  int t = blockIdx.x;
  int d = threadIdx.x * 8;
  int s0 = slot_of[t * 2 + 0], s1 = slot_of[t * 2 + 1];
  float w0 = route_w[t * 2 + 0], w1 = route_w[t * 2 + 1];
  float v0[8], v1[8];
#pragma unroll
  for (int j = 0; j < 8; ++j) { v0[j] = 0.f; v1[j] = 0.f; }
#pragma unroll
  for (int ks = 0; ks < KSPL; ++ks) {
    bf16x8 y0 = *(const bf16x8*)(ybuf + (size_t)ks * YSZ + (size_t)s0 * DDIM + d);
    bf16x8 y1 = *(const bf16x8*)(ybuf + (size_t)ks * YSZ + (size_t)s1 * DDIM + d);
#pragma unroll
    for (int j = 0; j < 8; ++j) {
      v0[j] += bf2f((unsigned short)y0[j]);
      v1[j] += bf2f((unsigned short)y1[j]);
    }
  }
  float* op = out + (size_t)t * DDIM + d;
#pragma unroll
  for (int j = 0; j < 8; ++j)
    op[j] = w0 * v0[j] + w1 * v1[j];
}

// =====================================================================
// GEMM1: g = silu(Xe w1^T) * (Xe w3^T); 256x256 tile, BK=64, 8 waves,
// r15 schedule; compact grid via tmap (r13-validated).
// =====================================================================
__global__ __launch_bounds__(512, 2) void gemm1_kernel(
    const unsigned short* __restrict__ xbf, const unsigned short* __restrict__ w1b,
    const unsigned short* __restrict__ w3b, const int* __restrict__ tok_list,
    const int* __restrict__ counts, const int* __restrict__ offsets,
    const int* __restrict__ tmap,
    unsigned short* __restrict__ g, int expert_fixed) {
  __shared__ __align__(16) char smem[133120];
  constexpr int NI = DDIM / 128;                // 16 iterations (2 K-tiles each)

  int nwg = gridDim.x;
  int orig = blockIdx.x;
  int wg = (orig & 7) * (nwg >> 3) + (orig >> 3);   // bijective XCD swizzle (nwg%8==0)
  int e, mbase, nt;
  if (expert_fixed >= 0) {
    e = expert_fixed;
    mbase = (wg & (MT - 1)) * 256;
    nt = (wg >> 5) % NT1;
  } else {
    int tl = wg % NTILE_MAX;
    nt = wg / NTILE_MAX;
    if (tl >= tmap[0]) return;
    int pk = tmap[1 + tl];
    e = pk >> 16;
    mbase = (pk & 0xffff) * 256;
  }
  int cnt = counts[e];
  if (mbase >= cnt) return;
  int off = offsets[e];
  int gshift = expert_fixed >= 0 ? 0 : off;
  int rows = cnt - mbase; if (rows > 256) rows = 256;

  const unsigned short* w1e = expert_fixed >= 0 ? w1b : w1b + (size_t)e * HDIM * DDIM;
  const unsigned short* w3e = expert_fixed >= 0 ? w3b : w3b + (size_t)e * HDIM * DDIM;

  int tid = threadIdx.x, lane = tid & 63, wid = tid >> 6;
  int wr = wid >> 2, wc = wid & 3;

  int r16 = lane >> 2;
  int csrc = (lane & 3) ^ ((lane >> 3) & 3);
  const char* asrc[2]; const char* bsrc[2];
#pragma unroll
  for (int j = 0; j < 2; ++j) {
    int r = wid * 32 + j * 16 + r16;
    int m = mbase + r; if (m > cnt - 1) m = cnt - 1;
    int tok = tok_list[off + m];
    asrc[j] = (const char*)xbf + (size_t)tok * (DDIM * 2) + csrc * 16;
    const char* base = (r < 128)
        ? (const char*)w1e + (size_t)(nt * 128 + r) * (DDIM * 2)
        : (const char*)w3e + (size_t)(nt * 128 + r - 128) * (DDIM * 2);
    bsrc[j] = base + csrc * 16;
  }
  int rA = (wr * 128 + (lane & 15)) * 64 + (((lane >> 4) ^ ((lane >> 1) & 3)) * 16);
  int rB = (wc * 64  + (lane & 15)) * 64 + (((lane >> 4) ^ ((lane >> 1) & 3)) * 16);

  f32x4 zv = {0.f, 0.f, 0.f, 0.f};
  f32x4 acc[8][4];
#pragma unroll
  for (int m = 0; m < 8; ++m)
#pragma unroll
    for (int n = 0; n < 4; ++n) acc[m][n] = zv;
  bf16x8 af[4], bfr[4];

  PROLOGUE();
#pragma unroll 1
  for (int i = 0; i < NI - 1; ++i) {
    size_t kb = (size_t)i * 256;
    ITER_FULL(kb);
  }
  {
    size_t kb = (size_t)(NI - 1) * 256;
    ITER_LAST(kb);
  }

  // epilogue: h1 (wc<2) -> LDS; h3 (wc>=2) computes g = silu(h1)*h3
  float* hb = (float*)smem;                       // [256][130] f32
  if (wc < 2) {
#pragma unroll
    for (int m = 0; m < 8; ++m)
#pragma unroll
      for (int q = 0; q < 4; ++q) {
        int row = wr * 128 + m * 16 + (lane >> 4) * 4 + q;
        int col = wc * 64 + (lane & 15);
#pragma unroll
        for (int n = 0; n < 4; ++n)
          hb[row * 130 + col + n * 16] = acc[m][n][q];
      }
  }
  asm volatile("s_waitcnt lgkmcnt(0)" ::: "memory");
  wg_barrier();
  if (wc >= 2) {
#pragma unroll
    for (int m = 0; m < 8; ++m)
#pragma unroll
      for (int q = 0; q < 4; ++q) {
        int row = wr * 128 + m * 16 + (lane >> 4) * 4 + q;
        if (row >= rows) continue;
        size_t grow = (size_t)(mbase + row + gshift);
        int colbase = (wc - 2) * 64 + (lane & 15);
        unsigned short* gp = g + grow * HDIM + nt * 128 + colbase;
#pragma unroll
        for (int n = 0; n < 4; ++n) {
          float h1 = hb[row * 130 + colbase + n * 16];
          float h3 = acc[m][n][q];
          float gv = (h1 / (1.f + __expf(-h1))) * h3;
          gp[n * 16] = f2bf(gv);
        }
      }
  }
}

// =====================================================================
// GEMM2: y = g @ w2 per packed slot; split-K=2 (non-atomic bf16 partial
// per K-half into ybuf[ks]); nt/ks-fast decode; Path B: atomic f32.
// =====================================================================
__global__ __launch_bounds__(512, 2) void gemm2_kernel(
    const unsigned short* __restrict__ g, const unsigned short* __restrict__ w2t,
    const int* __restrict__ tok_list, const float* __restrict__ tok_w,
    const int* __restrict__ counts, const int* __restrict__ offsets,
    const int* __restrict__ tmap,
    unsigned short* __restrict__ ybuf, float* __restrict__ out, int expert_fixed) {
  __shared__ __align__(16) char smem[131072];
  constexpr int NI = HDIM / 128 / KSPL;         // 28 iterations per K-half

  int nwg = gridDim.x;
  int orig = blockIdx.x;
  int wg = (orig & 7) * (nwg >> 3) + (orig >> 3);
  int e, mbase, nt, ks;
  if (expert_fixed >= 0) {
    e = expert_fixed;
    nt = wg % NT2;
    ks = (wg / NT2) % KSPL;
    mbase = (wg / (NT2 * KSPL)) * 256;
  } else {
    nt = wg % NT2;
    ks = (wg / NT2) % KSPL;
    int tl = wg / (NT2 * KSPL);   // nt,ks fast: 16 blocks of a tile adjacent
    if (tl >= tmap[0]) return;
    int pk = tmap[1 + tl];
    e = pk >> 16;
    mbase = (pk & 0xffff) * 256;
  }
  int cnt = counts[e];
  if (mbase >= cnt) return;
  int off = offsets[e];
  int gshift = expert_fixed >= 0 ? 0 : off;
  int nbase = nt * 256;
  int rows = cnt - mbase; if (rows > 256) rows = 256;
  const unsigned short* w2te = w2t + (expert_fixed >= 0 ? (size_t)0 : (size_t)e * DDIM * HDIM);
  size_t koff = (size_t)ks * (NI * 256);        // byte offset of this K-window

  int tid = threadIdx.x, lane = tid & 63, wid = tid >> 6;
  int wr = wid >> 2, wc = wid & 3;

  int r16 = lane >> 2;
  int csrc = (lane & 3) ^ ((lane >> 3) & 3);
  const char* asrc[2]; const char* bsrc[2];
#pragma unroll
  for (int j = 0; j < 2; ++j) {
    int r = wid * 32 + j * 16 + r16;
    int m = mbase + r; if (m > cnt - 1) m = cnt - 1;
    asrc[j] = (const char*)g + (size_t)(m + gshift) * (HDIM * 2) + csrc * 16 + koff;
    bsrc[j] = (const char*)w2te + (size_t)(nbase + r) * (HDIM * 2) + csrc * 16 + koff;
  }
  int rA = (wr * 128 + (lane & 15)) * 64 + (((lane >> 4) ^ ((lane >> 1) & 3)) * 16);
  int rB = (wc * 64  + (lane & 15)) * 64 + (((lane >> 4) ^ ((lane >> 1) & 3)) * 16);

  f32x4 zv = {0.f, 0.f, 0.f, 0.f};
  f32x4 acc[8][4];
#pragma unroll
  for (int m = 0; m < 8; ++m)
#pragma unroll
    for (int n = 0; n < 4; ++n) acc[m][n] = zv;
  bf16x8 af[4], bfr[4];

  PROLOGUE();
#pragma unroll 1
  for (int i = 0; i < NI - 1; ++i) {
    size_t kb = (size_t)i * 256;
    ITER_FULL(kb);
  }
  {
    size_t kb = (size_t)(NI - 1) * 256;
    ITER_LAST(kb);
  }

  if (ybuf) {
    unsigned short* yb = ybuf + (size_t)ks * ((size_t)TT * 2 * DDIM);
#pragma unroll
    for (int m = 0; m < 8; ++m)
#pragma unroll
      for (int q = 0; q < 4; ++q) {
        int row = wr * 128 + m * 16 + (lane >> 4) * 4 + q;
        if (row >= rows) continue;
        size_t slot = (size_t)(off + mbase + row);
        unsigned short* yp = yb + slot * DDIM + nbase + wc * 64 + (lane & 15);
#pragma unroll
        for (int n = 0; n < 4; ++n)
          yp[n * 16] = f2bf(acc[m][n][q]);
      }
  } else {
#pragma unroll
    for (int m = 0; m < 8; ++m)
#pragma unroll
      for (int q = 0; q < 4; ++q) {
        int row = wr * 128 + m * 16 + (lane >> 4) * 4 + q;
        if (row >= rows) continue;
        int mi = mbase + row;
        int tok = tok_list[off + mi];
        float wt = tok_w[off + mi];
        float* op = out + (size_t)tok * DDIM + nbase + wc * 64 + (lane & 15);
#pragma unroll
        for (int n = 0; n < 4; ++n)
          atomicAdd(op + n * 16, acc[m][n][q] * wt);
      }
  }
}

extern "C" void kernel_launch(void* const* d_in, const int* in_sizes, int n_in,
                              void* d_out, int out_size, void* d_ws, size_t ws_size,
                              hipStream_t stream) {
  const float* x      = (const float*)d_in[0];
  const float* gate_w = (const float*)d_in[1];
  const float* w1     = (const float*)d_in[2];
  const float* w2     = (const float*)d_in[3];
  const float* w3     = (const float*)d_in[4];
  float* out = (float*)d_out;
  char* ws = (char*)d_ws;

  size_t o = 0;
  int* counts  = (int*)(ws + o);
  int* offsets = counts + 8;
  int* cursor  = counts + 16;
  int* tmap    = counts + 24;          // tmap[0]=ntile, entries 1..NTILE_MAX
  o += 1024;
  int*   route_e = (int*)(ws + o);   o += (size_t)TT * 2 * 4;
  float* route_w = (float*)(ws + o); o += (size_t)TT * 2 * 4;
  int*   tok_list = (int*)(ws + o);  o += (size_t)TT * 2 * 4;
  float* tok_w = (float*)(ws + o);   o += (size_t)TT * 2 * 4;
  int*   slot_of = (int*)(ws + o);   o += (size_t)TT * 2 * 4;
  unsigned short* xbf = (unsigned short*)(ws + o); o += (size_t)TT * DDIM * 2;
  size_t fixed = o;

  const size_t WSZ = (size_t)HDIM * DDIM;
  const size_t wbf_full = (size_t)NEXP * WSZ * 2;
  const size_t gfull = (size_t)TT * 2 * HDIM * 2;

  hipMemsetAsync(counts, 0, 8 * sizeof(int), stream);
  gate_kernel<<<TT, 256, 0, stream>>>(x, gate_w, route_e, route_w, counts, xbf);
  scan_kernel<<<1, 64, 0, stream>>>(counts, offsets, cursor, tmap);
  scatter_kernel<<<(TT + 255) / 256, 256, 0, stream>>>(route_e, route_w, cursor,
                                                       tok_list, tok_w, slot_of);

  if (ws_size >= fixed + 3 * wbf_full + gfull) {
    unsigned short* w1b = (unsigned short*)(ws + fixed);
    unsigned short* w3b = w1b + NEXP * WSZ;
    unsigned short* w2t = w3b + NEXP * WSZ;
    unsigned short* gbuf = w2t + NEXP * WSZ;
    // ybuf: 2 K-half partial buffers (2 x 67MB = 134MB) alias w1b (235MB,
    // dead after gemm1)
    unsigned short* ybuf = w1b;
    cvt_bf16_kernel<<<8192, 256, 0, stream>>>(w1, w1b, (long)(NEXP * WSZ / 8));
    cvt_bf16_kernel<<<8192, 256, 0, stream>>>(w3, w3b, (long)(NEXP * WSZ / 8));
    transpose_w2_kernel<<<dim3(HDIM / 64, DDIM / 64, NEXP), 256, 0, stream>>>(w2, w2t, -1);
    gemm1_kernel<<<NTILE_MAX * NT1, 512, 0, stream>>>(
        xbf, w1b, w3b, tok_list, counts, offsets, tmap, gbuf, -1);
    gemm2_kernel<<<NTILE_MAX * NT2 * KSPL, 512, 0, stream>>>(
        gbuf, w2t, tok_list, tok_w, counts, offsets, tmap, ybuf, out, -1);
    reduce_kernel<<<TT, 256, 0, stream>>>(ybuf, slot_of, route_w, out);
  } else {
    unsigned short* w1b = (unsigned short*)(ws + fixed);
    unsigned short* w3b = w1b + WSZ;
    unsigned short* w2t = w3b + WSZ;
    unsigned short* gbuf = w2t + WSZ;
    hipMemsetAsync(out, 0, (size_t)TT * DDIM * sizeof(float), stream);
    for (int e = 0; e < NEXP; ++e) {
      cvt_bf16_kernel<<<4096, 256, 0, stream>>>(w1 + (size_t)e * WSZ, w1b, (long)(WSZ / 8));
      cvt_bf16_kernel<<<4096, 256, 0, stream>>>(w3 + (size_t)e * WSZ, w3b, (long)(WSZ / 8));
      transpose_w2_kernel<<<dim3(HDIM / 64, DDIM / 64, 1), 256, 0, stream>>>(w2, w2t, e);
      gemm1_kernel<<<MT * NT1, 512, 0, stream>>>(
          xbf, w1b, w3b, tok_list, counts, offsets, tmap, gbuf, e);
      gemm2_kernel<<<MT * NT2 * KSPL, 512, 0, stream>>>(
          gbuf, w2t, tok_list, tok_w, counts, offsets, tmap, (unsigned short*)0, out, e);
    }
  }
}